// Round 12
// baseline (3485.912 us; speedup 1.0000x reference)
//
#include <hip/hip_runtime.h>
#include <math.h>

typedef unsigned short u16;
typedef short short8 __attribute__((ext_vector_type(8)));
typedef short short4v __attribute__((ext_vector_type(4)));
typedef float f32x4 __attribute__((ext_vector_type(4)));

#define NLAYER 4
#define HDIM 1024
#define NHEAD 16
#define NKVH 4
#define FFDIM 2048
#define NEXP 8
#define SEQ 2048
#define NBATCH 2
#define NTOK (NBATCH*SEQ)
#define NPAIR (NTOK*2)
#define RMS_EPS 1e-5f

// ---- 2-term bf16 split: x = b2f(o0)+b2f(o1) + O(x*2^-18) ----
__device__ __forceinline__ u16 b16(float x) {
  unsigned u = __builtin_bit_cast(unsigned, x);
  unsigned r = (u + 0x7FFFu + ((u >> 16) & 1u)) >> 16;
  return (u16)r;
}
__device__ __forceinline__ float b2f(u16 b) {
  return __builtin_bit_cast(float, ((unsigned)b) << 16);
}
__device__ __forceinline__ void split2(float x, u16& o0, u16& o1) {
  o0 = b16(x); o1 = b16(x - b2f(o0));
}
__device__ __forceinline__ float clip100(float v) {
  return fminf(fmaxf(v, -100.f), 100.f);
}
// chunked XCD swizzle (nwg % 8 == 0)
__device__ __forceinline__ int swz8(int bid, int nwg) {
  return (bid & 7) * (nwg >> 3) + (bid >> 3);
}

// ---------------- RMSNorm: fp32 -> pre-split bf16 hi/lo ----------------
__global__ __launch_bounds__(256)
void rmsnorm_kernel(const float* __restrict__ x, const float* __restrict__ w,
                    u16* __restrict__ oh, u16* __restrict__ ol) {
  int t = blockIdx.x, tid = threadIdx.x;
  const float* xr = x + (long)t * HDIM;
  float4 v = *(const float4*)(xr + tid * 4);
  float ss = v.x*v.x + v.y*v.y + v.z*v.z + v.w*v.w;
  #pragma unroll
  for (int m = 32; m; m >>= 1) ss += __shfl_xor(ss, m);
  __shared__ float sb[4];
  if ((tid & 63) == 0) sb[tid >> 6] = ss;
  __syncthreads();
  ss = sb[0] + sb[1] + sb[2] + sb[3];
  float sc = 1.0f / sqrtf(ss * (1.f/HDIM) + RMS_EPS);
  float4 wv = *(const float4*)(w + tid * 4);
  float ov[4] = {v.x*sc*wv.x, v.y*sc*wv.y, v.z*sc*wv.z, v.w*sc*wv.w};
  short4v hv, lv;
  #pragma unroll
  for (int j = 0; j < 4; j++) { u16 h, l; split2(ov[j], h, l); hv[j]=(short)h; lv[j]=(short)l; }
  *(short4v*)&oh[(long)t*HDIM + tid*4] = hv;
  *(short4v*)&ol[(long)t*HDIM + tid*4] = lv;
}

// ---------------- RoPE cos/sin table ----------------
__global__ __launch_bounds__(256)
void rope_table_kernel(float* __restrict__ tab) {
  int idx = blockIdx.x * 256 + threadIdx.x;   // SEQ*32
  int i = idx & 31, pos = idx >> 5;
  double e = -(double)i * 0.28782313662425575;   // ln(10000)/32
  float inv = (float)exp(e);
  float f = (float)pos * inv;
  tab[idx] = cosf(f);
  tab[SEQ*32 + idx] = sinf(f);
}

#define GPAD 40

// =========== pipelined GEMM core BM=128, BN=64 (wave = 32 rows x 64 cols) ==========
__device__ __forceinline__ void gemm_core128(
    const u16* __restrict__ Ah, const u16* __restrict__ Al, long arow,
    const float* __restrict__ Bp, int Nb, int bcol0, int K,
    u16 (&As)[2][128][GPAD], u16 (&Bs)[2][64][GPAD],
    int tid, int wr, int lr, int lg, f32x4 (&acc)[2][4])
{
  int a_r = tid >> 1, a_kq = (tid & 1) * 16;
  int b_col = tid & 63;
  int b_kh = (tid >> 6) * 8;
  short8 pA[4];
  float pB[8];
  short8 cBh, cBl;
  auto loadA = [&](int k0) {
    if (arow >= 0) {
      const u16* ah = Ah + arow * (long)K + k0 + a_kq;
      const u16* al = Al + arow * (long)K + k0 + a_kq;
      pA[0] = *(const short8*)ah;
      pA[1] = *(const short8*)(ah + 8);
      pA[2] = *(const short8*)al;
      pA[3] = *(const short8*)(al + 8);
    } else {
      short8 z = {0,0,0,0,0,0,0,0};
      #pragma unroll
      for (int q = 0; q < 4; q++) pA[q] = z;
    }
  };
  auto loadB = [&](int k0) {
    const float* bp = Bp + (long)(k0 + b_kh) * Nb + bcol0 + b_col;
    #pragma unroll
    for (int j = 0; j < 8; j++) pB[j] = bp[(long)j * Nb];
  };
  auto convB = [&]() {
    #pragma unroll
    for (int j = 0; j < 8; j++) {
      u16 h, l; split2(pB[j], h, l);
      cBh[j] = (short)h; cBl[j] = (short)l;
    }
  };
  loadA(0); loadB(0); convB();
  for (int k0 = 0; k0 < K; k0 += 32) {
    if (k0) __syncthreads();
    *(short8*)&As[0][a_r][a_kq]     = pA[0];
    *(short8*)&As[0][a_r][a_kq + 8] = pA[1];
    *(short8*)&As[1][a_r][a_kq]     = pA[2];
    *(short8*)&As[1][a_r][a_kq + 8] = pA[3];
    *(short8*)&Bs[0][b_col][b_kh] = cBh;
    *(short8*)&Bs[1][b_col][b_kh] = cBl;
    __syncthreads();
    int kn = k0 + 32;
    if (kn < K) { loadA(kn); loadB(kn); }
    short8 bf[2][4];
    #pragma unroll
    for (int t = 0; t < 2; t++)
      #pragma unroll
      for (int n = 0; n < 4; n++)
        bf[t][n] = *(const short8*)&Bs[t][n*16 + lr][lg*8];
    #pragma unroll
    for (int m = 0; m < 2; m++) {
      short8 afh = *(const short8*)&As[0][wr + m*16 + lr][lg*8];
      short8 afl = *(const short8*)&As[1][wr + m*16 + lr][lg*8];
      #pragma unroll
      for (int n = 0; n < 4; n++) {
        f32x4 a = acc[m][n];
        a = __builtin_amdgcn_mfma_f32_16x16x32_bf16(afh, bf[0][n], a, 0, 0, 0);
        a = __builtin_amdgcn_mfma_f32_16x16x32_bf16(afh, bf[1][n], a, 0, 0, 0);
        a = __builtin_amdgcn_mfma_f32_16x16x32_bf16(afl, bf[0][n], a, 0, 0, 0);
        acc[m][n] = a;
      }
    }
    if (kn < K) convB();
  }
}

// ---------- down-proj: BM=128, BN=128, per-expert slot rows, Cf = acc ----------
__global__ __launch_bounds__(256)
void gemm_down(const u16* __restrict__ Ah, const u16* __restrict__ Al,
               const float* __restrict__ B, float* __restrict__ Cf,
               const int* __restrict__ offs, int N, int K, long bstride)
{
  __shared__ u16 As[2][128][GPAD];
  __shared__ u16 Bs[2][128][GPAD];
  int nwg = gridDim.x;            // 2048
  int bid = swz8(blockIdx.x, nwg);
  int cpe = nwg >> 3;             // 256 per expert (covers 4096 rows worst case)
  int z = bid / cpe, rr2 = bid % cpe;
  int rs = offs[z], re = offs[z + 1];
  int brow = rr2 >> 3, bcol = rr2 & 7;
  int p0 = rs + brow * 128;
  if (p0 >= re) return;
  int bcol0 = bcol * 128;
  const float* Bp = B + (long)z * bstride;
  int tid = threadIdx.x, wv = tid >> 6, lane = tid & 63;
  int lr = lane & 15, lg = lane >> 4;
  int wr = wv * 32;
  int a_r = tid >> 1, a_kq = (tid & 1) * 16;
  long arow = -1;
  { int rr = p0 + a_r; if (rr < re) arow = rr; }
  f32x4 acc[2][8];
  #pragma unroll
  for (int m = 0; m < 2; m++)
    #pragma unroll
    for (int n = 0; n < 8; n++) acc[m][n] = {0.f,0.f,0.f,0.f};
  int b_col = tid & 127;
  int b_kh = (tid >> 7) * 16;
  short8 pA[4];
  float pB[16];
  short8 cB0, cB1, cB2, cB3;   // hi[0:8], hi[8:16], lo[0:8], lo[8:16]
  auto loadA = [&](int k0) {
    if (arow >= 0) {
      const u16* ah = Ah + arow * (long)K + k0 + a_kq;
      const u16* al = Al + arow * (long)K + k0 + a_kq;
      pA[0] = *(const short8*)ah;
      pA[1] = *(const short8*)(ah + 8);
      pA[2] = *(const short8*)al;
      pA[3] = *(const short8*)(al + 8);
    } else {
      short8 z_ = {0,0,0,0,0,0,0,0};
      #pragma unroll
      for (int q = 0; q < 4; q++) pA[q] = z_;
    }
  };
  auto loadB = [&](int k0) {
    const float* bp = Bp + (long)(k0 + b_kh) * N + bcol0 + b_col;
    #pragma unroll
    for (int j = 0; j < 16; j++) pB[j] = bp[(long)j * N];
  };
  auto convB = [&]() {
    #pragma unroll
    for (int j = 0; j < 8; j++) {
      u16 h, l; split2(pB[j], h, l);
      cB0[j] = (short)h; cB2[j] = (short)l;
    }
    #pragma unroll
    for (int j = 0; j < 8; j++) {
      u16 h, l; split2(pB[8 + j], h, l);
      cB1[j] = (short)h; cB3[j] = (short)l;
    }
  };
  loadA(0); loadB(0); convB();
  for (int k0 = 0; k0 < K; k0 += 32) {
    if (k0) __syncthreads();
    *(short8*)&As[0][a_r][a_kq]     = pA[0];
    *(short8*)&As[0][a_r][a_kq + 8] = pA[1];
    *(short8*)&As[1][a_r][a_kq]     = pA[2];
    *(short8*)&As[1][a_r][a_kq + 8] = pA[3];
    *(short8*)&Bs[0][b_col][b_kh]     = cB0;
    *(short8*)&Bs[0][b_col][b_kh + 8] = cB1;
    *(short8*)&Bs[1][b_col][b_kh]     = cB2;
    *(short8*)&Bs[1][b_col][b_kh + 8] = cB3;
    __syncthreads();
    int kn = k0 + 32;
    if (kn < K) { loadA(kn); loadB(kn); }
    short8 afh[2], afl[2];
    #pragma unroll
    for (int m = 0; m < 2; m++) {
      afh[m] = *(const short8*)&As[0][wr + m*16 + lr][lg*8];
      afl[m] = *(const short8*)&As[1][wr + m*16 + lr][lg*8];
    }
    #pragma unroll
    for (int n = 0; n < 8; n++) {
      short8 bh = *(const short8*)&Bs[0][n*16 + lr][lg*8];
      short8 bl = *(const short8*)&Bs[1][n*16 + lr][lg*8];
      #pragma unroll
      for (int m = 0; m < 2; m++) {
        f32x4 a = acc[m][n];
        a = __builtin_amdgcn_mfma_f32_16x16x32_bf16(afh[m], bh, a, 0, 0, 0);
        a = __builtin_amdgcn_mfma_f32_16x16x32_bf16(afh[m], bl, a, 0, 0, 0);
        a = __builtin_amdgcn_mfma_f32_16x16x32_bf16(afl[m], bh, a, 0, 0, 0);
        acc[m][n] = a;
      }
    }
    if (kn < K) convB();
  }
  #pragma unroll
  for (int m = 0; m < 2; m++) {
    int row0 = p0 + wr + m*16 + lg*4;
    #pragma unroll
    for (int n = 0; n < 8; n++) {
      int col = bcol0 + n*16 + lr;
      #pragma unroll
      for (int r = 0; r < 4; r++) {
        int row = row0 + r;
        if (row < re) Cf[(long)row * N + col] = acc[m][n][r];
      }
    }
  }
}

// wo-proj: BM=128, Cf = clip(Cf + acc).
__global__ __launch_bounds__(256)
void gemm_wo(const u16* __restrict__ Ah, const u16* __restrict__ Al,
             const float* __restrict__ B, float* __restrict__ Cf,
             int M, int N, int K, int ncol)
{
  __shared__ u16 As[2][128][GPAD];
  __shared__ u16 Bs[2][64][GPAD];
  int bid = swz8(blockIdx.x, gridDim.x);
  int brow = bid / ncol, bcol = bid % ncol;
  int p0 = brow * 128;
  int bcol0 = bcol * 64;
  int tid = threadIdx.x, wv = tid >> 6, lane = tid & 63;
  int lr = lane & 15, lg = lane >> 4;
  int wr = wv * 32;
  long arow = p0 + (tid >> 1);
  f32x4 acc[2][4];
  #pragma unroll
  for (int m = 0; m < 2; m++)
    #pragma unroll
    for (int n = 0; n < 4; n++) acc[m][n] = {0.f,0.f,0.f,0.f};
  gemm_core128(Ah, Al, arow, B, N, bcol0, K, As, Bs, tid, wr, lr, lg, acc);
  #pragma unroll
  for (int m = 0; m < 2; m++) {
    int row0 = p0 + wr + m*16 + lg*4;
    #pragma unroll
    for (int n = 0; n < 4; n++) {
      int col = bcol0 + n*16 + lr;
      #pragma unroll
      for (int r = 0; r < 4; r++) {
        long idx = (long)(row0 + r) * N + col;
        Cf[idx] = clip100(Cf[idx] + acc[m][n][r]);
      }
    }
  }
}

// ---------- fused MoE gate+up GEMM, BM=128 (64 AGPR -> 3 waves/SIMD) ----------
// h = silu(x@wg) * (x@wu), pre-split bf16 hi/lo output.
__global__ __launch_bounds__(256)
void gemm_gateup(const u16* __restrict__ Ah, const u16* __restrict__ Al,
                 const float* __restrict__ Bg, const float* __restrict__ Bu,
                 u16* __restrict__ Ch, u16* __restrict__ Cl,
                 const int* __restrict__ gather, const int* __restrict__ offs)
{
  __shared__ u16 As[2][128][GPAD];
  __shared__ u16 Bgs[2][64][GPAD];
  __shared__ u16 Bus[2][64][GPAD];
  const int K = HDIM, N = FFDIM;
  int nwg = gridDim.x;                    // 16384 = 8 exp * 64 row * 32 col
  int bid = swz8(blockIdx.x, nwg);
  int cpe = nwg >> 3;                     // 2048 per expert
  int z = bid / cpe, rr2 = bid % cpe;
  int rs = offs[z], re = offs[z + 1];
  int brow = rr2 >> 5, bcol = rr2 & 31;
  int p0 = rs + brow * 128;
  if (p0 >= re) return;
  int bcol0 = bcol * 64;
  const float* Bpg = Bg + (long)z * ((long)HDIM * FFDIM);
  const float* Bpu = Bu + (long)z * ((long)HDIM * FFDIM);
  int tid = threadIdx.x, wv = tid >> 6, lane = tid & 63;
  int lr = lane & 15, lg = lane >> 4;
  int wr = wv * 32;
  int a_r = tid >> 1, a_kq = (tid & 1) * 16;
  long arow = -1;
  { int rr = p0 + a_r; if (rr < re) arow = gather[rr]; }
  f32x4 accg[2][4], accu[2][4];
  #pragma unroll
  for (int m = 0; m < 2; m++)
    #pragma unroll
    for (int n = 0; n < 4; n++) { accg[m][n] = {0.f,0.f,0.f,0.f}; accu[m][n] = {0.f,0.f,0.f,0.f}; }
  int b_col = tid & 63;
  int b_kh = (tid >> 6) * 8;
  short8 pA[4];
  float pBg[8], pBu[8];
  short8 cGh, cGl, cUh, cUl;
  auto loadA = [&](int k0) {
    if (arow >= 0) {
      const u16* ah = Ah + arow * (long)K + k0 + a_kq;
      const u16* al = Al + arow * (long)K + k0 + a_kq;
      pA[0] = *(const short8*)ah;
      pA[1] = *(const short8*)(ah + 8);
      pA[2] = *(const short8*)al;
      pA[3] = *(const short8*)(al + 8);
    } else {
      short8 zz = {0,0,0,0,0,0,0,0};
      #pragma unroll
      for (int q = 0; q < 4; q++) pA[q] = zz;
    }
  };
  auto loadB = [&](int k0) {
    const float* bpg = Bpg + (long)(k0 + b_kh) * N + bcol0 + b_col;
    const float* bpu = Bpu + (long)(k0 + b_kh) * N + bcol0 + b_col;
    #pragma unroll
    for (int j = 0; j < 8; j++) { pBg[j] = bpg[(long)j * N]; pBu[j] = bpu[(long)j * N]; }
  };
  auto convB = [&]() {
    #pragma unroll
    for (int j = 0; j < 8; j++) {
      u16 h, l;
      split2(pBg[j], h, l); cGh[j] = (short)h; cGl[j] = (short)l;
      split2(pBu[j], h, l); cUh[j] = (short)h; cUl[j] = (short)l;
    }
  };
  loadA(0); loadB(0); convB();
  for (int k0 = 0; k0 < K; k0 += 32) {
    if (k0) __syncthreads();
    *(short8*)&As[0][a_r][a_kq]     = pA[0];
    *(short8*)&As[0][a_r][a_kq + 8] = pA[1];
    *(short8*)&As[1][a_r][a_kq]     = pA[2];
    *(short8*)&As[1][a_r][a_kq + 8] = pA[3];
    *(short8*)&Bgs[0][b_col][b_kh] = cGh;
    *(short8*)&Bgs[1][b_col][b_kh] = cGl;
    *(short8*)&Bus[0][b_col][b_kh] = cUh;
    *(short8*)&Bus[1][b_col][b_kh] = cUl;
    __syncthreads();
    int kn = k0 + 32;
    if (kn < K) { loadA(kn); loadB(kn); }
    short8 afh[2], afl[2];
    #pragma unroll
    for (int m = 0; m < 2; m++) {
      afh[m] = *(const short8*)&As[0][wr + m*16 + lr][lg*8];
      afl[m] = *(const short8*)&As[1][wr + m*16 + lr][lg*8];
    }
    #pragma unroll
    for (int n = 0; n < 4; n++) {
      short8 bgh = *(const short8*)&Bgs[0][n*16 + lr][lg*8];
      short8 bgl = *(const short8*)&Bgs[1][n*16 + lr][lg*8];
      short8 buh = *(const short8*)&Bus[0][n*16 + lr][lg*8];
      short8 bul = *(const short8*)&Bus[1][n*16 + lr][lg*8];
      #pragma unroll
      for (int m = 0; m < 2; m++) {
        f32x4 g = accg[m][n];
        g = __builtin_amdgcn_mfma_f32_16x16x32_bf16(afh[m], bgh, g, 0, 0, 0);
        g = __builtin_amdgcn_mfma_f32_16x16x32_bf16(afh[m], bgl, g, 0, 0, 0);
        g = __builtin_amdgcn_mfma_f32_16x16x32_bf16(afl[m], bgh, g, 0, 0, 0);
        accg[m][n] = g;
        f32x4 u = accu[m][n];
        u = __builtin_amdgcn_mfma_f32_16x16x32_bf16(afh[m], buh, u, 0, 0, 0);
        u = __builtin_amdgcn_mfma_f32_16x16x32_bf16(afh[m], bul, u, 0, 0, 0);
        u = __builtin_amdgcn_mfma_f32_16x16x32_bf16(afl[m], buh, u, 0, 0, 0);
        accu[m][n] = u;
      }
    }
    if (kn < K) convB();
  }
  #pragma unroll
  for (int m = 0; m < 2; m++) {
    int row0 = p0 + wr + m*16 + lg*4;
    #pragma unroll
    for (int n = 0; n < 4; n++) {
      int col = bcol0 + n*16 + lr;
      #pragma unroll
      for (int r = 0; r < 4; r++) {
        int row = row0 + r;
        if (row < re) {
          float gv = accg[m][n][r], uv = accu[m][n][r];
          float hh = gv / (1.f + __expf(-gv)) * uv;
          u16 h, l; split2(hh, h, l);
          long idx = (long)row * N + col;
          Ch[idx] = h; Cl[idx] = l;
        }
      }
    }
  }
}

// fused QKV GEMM: BM=128, 1D grid 768 (bx 0..23 fast, 32 row panels), XCD swizzled
__global__ __launch_bounds__(256)
void gemm_qkv(const u16* __restrict__ Ah, const u16* __restrict__ Al,
              const float* __restrict__ wq, const float* __restrict__ wk,
              const float* __restrict__ wv_, const float* __restrict__ tab,
              u16* __restrict__ qh, u16* __restrict__ ql,
              u16* __restrict__ kh_, u16* __restrict__ kl_,
              u16* __restrict__ vth, u16* __restrict__ vtl)
{
  __shared__ u16 As[2][128][GPAD];
  __shared__ u16 Bs[2][64][GPAD];
  int bid = swz8(blockIdx.x, gridDim.x);
  int bx = bid % 24;
  int p0 = (bid / 24) * 128;
  const float* Bp; int Nb, bcol0;
  if (bx < 16)      { Bp = wq;  Nb = 1024; bcol0 = bx * 64; }
  else if (bx < 20) { Bp = wk;  Nb = 256;  bcol0 = (bx - 16) * 64; }
  else              { Bp = wv_; Nb = 256;  bcol0 = (bx - 20) * 64; }
  int K = HDIM;
  int tid = threadIdx.x, wv = tid >> 6, lane = tid & 63;
  int lr = lane & 15, lg = lane >> 4;
  int wr = wv * 32;
  long arow = p0 + (tid >> 1);
  f32x4 acc[2][4];
  #pragma unroll
  for (int m = 0; m < 2; m++)
    #pragma unroll
    for (int n = 0; n < 4; n++) acc[m][n] = {0.f,0.f,0.f,0.f};
  gemm_core128(Ah, Al, arow, Bp, Nb, bcol0, K, As, Bs, tid, wr, lr, lg, acc);
  if (bx < 16) {          // ---- q: rope + split ----
    int h = bx;
    #pragma unroll
    for (int m = 0; m < 2; m++) {
      #pragma unroll
      for (int r = 0; r < 4; r++) {
        int tok = p0 + wr + m*16 + lg*4 + r;
        int pos = tok & (SEQ - 1);
        #pragma unroll
        for (int n = 0; n < 2; n++) {
          int i = n*16 + lr;
          float c = tab[pos*32 + i], s = tab[SEQ*32 + pos*32 + i];
          float x0 = acc[m][n][r], x1 = acc[m][n+2][r];
          float y0 = x0*c - x1*s, y1 = x1*c + x0*s;
          long base = (long)tok*1024 + h*64 + i;
          u16 h0, l0; split2(y0, h0, l0); qh[base] = h0; ql[base] = l0;
          u16 h1, l1; split2(y1, h1, l1); qh[base+32] = h1; ql[base+32] = l1;
        }
      }
    }
  } else if (bx < 20) {   // ---- k: rope + split ----
    int kvh = bx - 16;
    #pragma unroll
    for (int m = 0; m < 2; m++) {
      #pragma unroll
      for (int r = 0; r < 4; r++) {
        int tok = p0 + wr + m*16 + lg*4 + r;
        int pos = tok & (SEQ - 1);
        #pragma unroll
        for (int n = 0; n < 2; n++) {
          int i = n*16 + lr;
          float c = tab[pos*32 + i], s = tab[SEQ*32 + pos*32 + i];
          float x0 = acc[m][n][r], x1 = acc[m][n+2][r];
          float y0 = x0*c - x1*s, y1 = x1*c + x0*s;
          long base = (long)tok*256 + kvh*64 + i;
          u16 h0, l0; split2(y0, h0, l0); kh_[base] = h0; kl_[base] = l0;
          u16 h1, l1; split2(y1, h1, l1); kh_[base+32] = h1; kl_[base+32] = l1;
        }
      }
    }
  } else {                // ---- v: split + transpose ----
    int kvh = bx - 20;
    #pragma unroll
    for (int m = 0; m < 2; m++) {
      #pragma unroll
      for (int r = 0; r < 4; r++) {
        int tok = p0 + wr + m*16 + lg*4 + r;
        int bb = tok >> 11, tl = tok & (SEQ - 1);
        #pragma unroll
        for (int n = 0; n < 4; n++) {
          int hd = n*16 + lr;
          u16 h0, l0; split2(acc[m][n][r], h0, l0);
          long vidx = ((long)(bb*NKVH + kvh)*64 + hd)*SEQ + tl;
          vth[vidx] = h0; vtl[vidx] = l0;
        }
      }
    }
  }
}

// ---------------- causal flash attention, pipelined K/V staging ----------------
#define ATP 70
#define PPAD 68
__global__ __launch_bounds__(256)
void attn_kernel(const u16* __restrict__ qhi, const u16* __restrict__ qlo,
                 const u16* __restrict__ khi, const u16* __restrict__ klo,
                 const u16* __restrict__ vthi, const u16* __restrict__ vtlo,
                 u16* __restrict__ ohi, u16* __restrict__ olo)
{
  int bid = swz8(blockIdx.x, gridDim.x);   // chunk 64 = one (b, kvh) group
  int qp = bid & 15, h = (bid >> 4) & 15, b = bid >> 8;
  int kvh = h >> 2;
  int tid = threadIdx.x, w = tid >> 6, lane = tid & 63;
  int lr = lane & 15, lg = lane >> 4;
  __shared__ u16 KhS[64][ATP], KlS[64][ATP], VhS[64][ATP], VlS[64][ATP];
  __shared__ u16 Ps[2][4][16][PPAD];
  long tokbase = (long)b * SEQ;
  int sr = tid >> 2, scg = (tid & 3) * 16;
  const u16* vrow_h = vthi + ((long)(b*NKVH + kvh)*64 + sr)*SEQ;
  const u16* vrow_l = vtlo + ((long)(b*NKVH + kvh)*64 + sr)*SEQ;
  short8 pK[4], pV[4];
  auto loadKV = [&](int kt) {
    long kg = (tokbase + kt*64 + sr)*256 + kvh*64 + scg;
    pK[0] = *(const short8*)(khi + kg);
    pK[1] = *(const short8*)(khi + kg + 8);
    pK[2] = *(const short8*)(klo + kg);
    pK[3] = *(const short8*)(klo + kg + 8);
    long vg = kt*64 + scg;
    pV[0] = *(const short8*)(vrow_h + vg);
    pV[1] = *(const short8*)(vrow_h + vg + 8);
    pV[2] = *(const short8*)(vrow_l + vg);
    pV[3] = *(const short8*)(vrow_l + vg + 8);
  };
  loadKV(0);

  for (int ph = 0; ph < 2; ph++) {
    int qt = ph ? (31 - qp) : qp;
    long q0 = (long)qt * 64;
    const u16* qh_row = qhi + (tokbase + q0 + w*16 + lr)*1024 + h*64;
    const u16* ql_row = qlo + (tokbase + q0 + w*16 + lr)*1024 + h*64;
    short8 aqh[2], aql[2];
    #pragma unroll
    for (int hf = 0; hf < 2; hf++) {
      aqh[hf] = *(const short8*)(qh_row + hf*32 + lg*8);
      aql[hf] = *(const short8*)(ql_row + hf*32 + lg*8);
    }
    f32x4 Oacc[4];
    #pragma unroll
    for (int n = 0; n < 4; n++) Oacc[n] = {0.f,0.f,0.f,0.f};
    float mrow[4] = {-1e30f,-1e30f,-1e30f,-1e30f};
    float lrow[4] = {0.f,0.f,0.f,0.f};
    for (int kt = 0; kt <= qt; kt++) {
      if (ph | kt) __syncthreads();     // prior LDS readers done
      *(short8*)&KhS[sr][scg]   = pK[0];
      *(short8*)&KhS[sr][scg+8] = pK[1];
      *(short8*)&KlS[sr][scg]   = pK[2];
      *(short8*)&KlS[sr][scg+8] = pK[3];
      *(short8*)&VhS[sr][scg]   = pV[0];
      *(short8*)&VhS[sr][scg+8] = pV[1];
      *(short8*)&VlS[sr][scg]   = pV[2];
      *(short8*)&VlS[sr][scg+8] = pV[3];
      __syncthreads();
      loadKV(kt < qt ? kt + 1 : 0);     // prefetch next tile (or next phase's 0)
      float sv[4][4];
      #pragma unroll
      for (int n = 0; n < 4; n++) {
        short8 bh0 = *(const short8*)&KhS[n*16 + lr][lg*8];
        short8 bh1 = *(const short8*)&KhS[n*16 + lr][32 + lg*8];
        short8 bl0 = *(const short8*)&KlS[n*16 + lr][lg*8];
        short8 bl1 = *(const short8*)&KlS[n*16 + lr][32 + lg*8];
        f32x4 c = {0.f,0.f,0.f,0.f};
        c = __builtin_amdgcn_mfma_f32_16x16x32_bf16(aqh[0], bh0, c, 0, 0, 0);
        c = __builtin_amdgcn_mfma_f32_16x16x32_bf16(aqh[1], bh1, c, 0, 0, 0);
        c = __builtin_amdgcn_mfma_f32_16x16x32_bf16(aqh[0], bl0, c, 0, 0, 0);
        c = __builtin_amdgcn_mfma_f32_16x16x32_bf16(aqh[1], bl1, c, 0, 0, 0);
        c = __builtin_amdgcn_mfma_f32_16x16x32_bf16(aql[0], bh0, c, 0, 0, 0);
        c = __builtin_amdgcn_mfma_f32_16x16x32_bf16(aql[1], bh1, c, 0, 0, 0);
        #pragma unroll
        for (int r = 0; r < 4; r++) sv[n][r] = c[r] * 0.125f;
      }
      if (kt == qt) {
        #pragma unroll
        for (int n = 0; n < 4; n++)
          #pragma unroll
          for (int r = 0; r < 4; r++)
            if (n*16 + lr > w*16 + lg*4 + r) sv[n][r] = -1e30f;
      }
      float pvv[4][4], alpha[4];
      #pragma unroll
      for (int r = 0; r < 4; r++) {
        float vm = fmaxf(fmaxf(sv[0][r], sv[1][r]), fmaxf(sv[2][r], sv[3][r]));
        #pragma unroll
        for (int msk = 1; msk < 16; msk <<= 1) vm = fmaxf(vm, __shfl_xor(vm, msk));
        float mnew = fmaxf(mrow[r], vm);
        alpha[r] = __expf(mrow[r] - mnew);
        float psum = 0.f;
        #pragma unroll
        for (int n = 0; n < 4; n++) { pvv[n][r] = __expf(sv[n][r] - mnew); psum += pvv[n][r]; }
        #pragma unroll
        for (int msk = 1; msk < 16; msk <<= 1) psum += __shfl_xor(psum, msk);
        lrow[r] = lrow[r] * alpha[r] + psum;
        mrow[r] = mnew;
      }
      #pragma unroll
      for (int n = 0; n < 4; n++)
        #pragma unroll
        for (int r = 0; r < 4; r++) {
          u16 t0, t1;
          split2(pvv[n][r], t0, t1);
          Ps[0][w][lg*4 + r][n*16 + lr] = t0;
          Ps[1][w][lg*4 + r][n*16 + lr] = t1;
        }
      #pragma unroll
      for (int n = 0; n < 4; n++)
        #pragma unroll
        for (int r = 0; r < 4; r++) Oacc[n][r] *= alpha[r];
      #pragma unroll
      for (int kk = 0; kk < 2; kk++) {
        short8 aph = *(const short8*)&Ps[0][w][lr][kk*32 + lg*8];
        short8 apl = *(const short8*)&Ps[1][w][lr][kk*32 + lg*8];
        #pragma unroll
        for (int n = 0; n < 4; n++) {
          short8 bvh = *(const short8*)&VhS[n*16 + lr][kk*32 + lg*8];
          short8 bvl = *(const short8*)&VlS[n*16 + lr][kk*32 + lg*8];
          f32x4 a = Oacc[n];
          a = __builtin_amdgcn_mfma_f32_16x16x32_bf16(aph, bvh, a, 0, 0, 0);
          a = __builtin_amdgcn_mfma_f32_16x16x32_bf16(aph, bvl, a, 0, 0, 0);
          a = __builtin_amdgcn_mfma_f32_16x16x32_bf16(apl, bvh, a, 0, 0, 0);
          Oacc[n] = a;
        }
      }
    }
    u16* oh_row = ohi + (tokbase + q0 + w*16)*1024 + h*64;
    u16* ol_row = olo + (tokbase + q0 + w*16)*1024 + h*64;
    #pragma unroll
    for (int n = 0; n < 4; n++)
      #pragma unroll
      for (int r = 0; r < 4; r++) {
        float v = Oacc[n][r] / lrow[r];
        u16 h0, l0; split2(v, h0, l0);
        oh_row[(lg*4 + r)*1024 + n*16 + lr] = h0;
        ol_row[(lg*4 + r)*1024 + n*16 + lr] = l0;
      }
  }
}

// ---------------- router (pure fp32) ----------------
__global__ __launch_bounds__(64)
void router_kernel(const float* __restrict__ x, const float* __restrict__ w2,
                   const float* __restrict__ wr, int* __restrict__ tok_e,
                   float* __restrict__ tok_w, int* __restrict__ counts)
{
  int t = blockIdx.x, l = threadIdx.x;
  const float* xr = x + (long)t * HDIM;
  float xv[16];
  float ss = 0.f;
  #pragma unroll
  for (int j = 0; j < 16; j++) { xv[j] = xr[l + j*64]; ss += xv[j]*xv[j]; }
  #pragma unroll
  for (int m = 32; m; m >>= 1) ss += __shfl_xor(ss, m);
  float sc = 1.0f / sqrtf(ss * (1.f/HDIM) + RMS_EPS);
  float acc[8] = {0,0,0,0,0,0,0,0};
  #pragma unroll
  for (int j = 0; j < 16; j++) {
    int hh = l + j*64;
    float xnv = xv[j] * sc * w2[hh];
    const float* wrow = wr + hh * 8;
    #pragma unroll
    for (int e = 0; e < 8; e++) acc[e] += xnv * wrow[e];
  }
  #pragma unroll
  for (int e = 0; e < 8; e++)
    #pragma unroll
    for (int m = 32; m; m >>= 1) acc[e] += __shfl_xor(acc[e], m);
  if (l == 0) {
    float mx = acc[0];
    #pragma unroll
    for (int e = 1; e < 8; e++) mx = fmaxf(mx, acc[e]);
    float ex[8], s = 0.f;
    #pragma unroll
    for (int e = 0; e < 8; e++) { ex[e] = expf(acc[e] - mx); s += ex[e]; }
    int e0 = 0;
    #pragma unroll
    for (int e = 1; e < 8; e++) if (ex[e] > ex[e0]) e0 = e;
    int e1 = (e0 == 0) ? 1 : 0;
    for (int e = 0; e < 8; e++) if (e != e0 && ex[e] > ex[e1]) e1 = e;
    float v0 = ex[e0] / s, v1 = ex[e1] / s, wsum = v0 + v1;
    tok_e[2*t] = e0; tok_e[2*t+1] = e1;
    tok_w[2*t] = v0 / wsum; tok_w[2*t+1] = v1 / wsum;
    atomicAdd(&counts[e0], 1);
    atomicAdd(&counts[e1], 1);
  }
}

__global__ void scan_kernel(const int* __restrict__ counts, int* __restrict__ offs,
                            int* __restrict__ cursor) {
  if (threadIdx.x == 0 && blockIdx.x == 0) {
    int s = 0;
    for (int e = 0; e < NEXP; e++) { offs[e] = s; cursor[e] = s; s += counts[e]; }
    offs[NEXP] = s;
  }
}

__global__ __launch_bounds__(256)
void scatter_kernel(const int* __restrict__ tok_e, int* __restrict__ cursor,
                    int* __restrict__ tok_of_pair, int* __restrict__ tok_slot) {
  int t = blockIdx.x * 256 + threadIdx.x;
  if (t >= NTOK) return;
  #pragma unroll
  for (int s = 0; s < 2; s++) {
    int e = tok_e[2*t + s];
    int pos = atomicAdd(&cursor[e], 1);
    tok_of_pair[pos] = t;
    tok_slot[2*t + s] = pos;
  }
}

// x = clip(x + w0*po[s0] + w1*po[s1])
__global__ __launch_bounds__(256)
void combine_kernel(float* __restrict__ x, const float* __restrict__ po,
                    const int* __restrict__ tok_slot, const float* __restrict__ tok_w) {
  int t = blockIdx.x, tid = threadIdx.x;
  long s0 = tok_slot[2*t], s1 = tok_slot[2*t+1];
  float w0 = tok_w[2*t], w1 = tok_w[2*t+1];
  int c = tid * 4;
  float4 xv = *(float4*)(x + (long)t*HDIM + c);
  float4 a  = *(const float4*)(po + s0*HDIM + c);
  float4 bb = *(const float4*)(po + s1*HDIM + c);
  xv.x = clip100(xv.x + w0*a.x + w1*bb.x);
  xv.y = clip100(xv.y + w0*a.y + w1*bb.y);
  xv.z = clip100(xv.z + w0*a.z + w1*bb.z);
  xv.w = clip100(xv.w + w0*a.w + w1*bb.w);
  *(float4*)(x + (long)t*HDIM + c) = xv;
}

extern "C" void kernel_launch(void* const* d_in, const int* in_sizes, int n_in,
                              void* d_out, int out_size, void* d_ws, size_t ws_size,
                              hipStream_t stream)
{
  (void)in_sizes; (void)n_in; (void)out_size; (void)ws_size;
  const float* hs  = (const float*)d_in[0];
  const float* ln1 = (const float*)d_in[1];
  const float* ln2 = (const float*)d_in[2];
  const float* wq  = (const float*)d_in[3];
  const float* wk  = (const float*)d_in[4];
  const float* wvv = (const float*)d_in[5];
  const float* wo  = (const float*)d_in[6];
  const float* wr  = (const float*)d_in[7];
  const float* wg  = (const float*)d_in[8];
  const float* wu  = (const float*)d_in[9];
  const float* wd  = (const float*)d_in[10];
  float* x = (float*)d_out;

  char* p = (char*)d_ws;
  auto carve = [&](size_t bytes) {
    char* r = p; p += (bytes + 255) & ~(size_t)255; return r;
  };
  float* tab = (float*)carve((size_t)SEQ * 32 * 2 * 4);
  u16* xnh = (u16*)carve((size_t)NTOK * HDIM * 2);
  u16* xnl = (u16*)carve((size_t)NTOK * HDIM * 2);
  char* R  = carve((size_t)128 * 1024 * 1024);   // shared attn / MoE region
  // attn phase layout
  u16* qhi = (u16*)R;                              // 8MB
  u16* qlo = (u16*)(R + 8u*1024*1024);             // 8MB
  u16* khi = (u16*)(R + 16u*1024*1024);            // 2MB
  u16* klo = (u16*)(R + 18u*1024*1024);            // 2MB
  u16* vthi= (u16*)(R + 20u*1024*1024);            // 2MB
  u16* vtlo= (u16*)(R + 22u*1024*1024);            // 2MB
  u16* ohi = (u16*)(R + 24u*1024*1024);            // 8MB
  u16* olo = (u16*)(R + 32u*1024*1024);            // 8MB
  // MoE phase layout (aliases attn; sequential stream order makes this safe)
  u16*   ghi = (u16*)R;                            // 32MB
  u16*   glo = (u16*)(R + 32u*1024*1024);          // 32MB
  float* po  = (float*)(R + 64u*1024*1024);        // 32MB
  int*   tok_e       = (int*)carve(NTOK * 2 * 4);
  float* tok_w       = (float*)carve(NTOK * 2 * 4);
  int*   tok_slot    = (int*)carve(NTOK * 2 * 4);
  int*   tok_of_pair = (int*)carve(NPAIR * 4);
  int*   counts      = (int*)carve(8 * 4);
  int*   offs        = (int*)carve(9 * 4);
  int*   cursor      = (int*)carve(8 * 4);

  hipMemcpyAsync(x, hs, (size_t)NTOK * HDIM * 4, hipMemcpyDeviceToDevice, stream);
  rope_table_kernel<<<SEQ*32/256, 256, 0, stream>>>(tab);

  for (int l = 0; l < NLAYER; l++) {
    rmsnorm_kernel<<<NTOK, 256, 0, stream>>>(x, ln1 + (long)l*HDIM, xnh, xnl);
    gemm_qkv<<<768, 256, 0, stream>>>(
        xnh, xnl, wq + (long)l*HDIM*1024, wk + (long)l*HDIM*256,
        wvv + (long)l*HDIM*256, tab, qhi, qlo, khi, klo, vthi, vtlo);
    attn_kernel<<<512, 256, 0, stream>>>(
        qhi, qlo, khi, klo, vthi, vtlo, ohi, olo);
    gemm_wo<<<512, 256, 0, stream>>>(
        ohi, olo, wo + (long)l*1024*HDIM, x, NTOK, HDIM, 1024, 16);

    rmsnorm_kernel<<<NTOK, 256, 0, stream>>>(x, ln2 + (long)l*HDIM, xnh, xnl);
    hipMemsetAsync(counts, 0, 8 * 4, stream);
    router_kernel<<<NTOK, 64, 0, stream>>>(
        x, ln2 + (long)l*HDIM, wr + (long)l*HDIM*NEXP, tok_e, tok_w, counts);
    scan_kernel<<<1, 64, 0, stream>>>(counts, offs, cursor);
    scatter_kernel<<<NTOK/256, 256, 0, stream>>>(tok_e, cursor, tok_of_pair, tok_slot);
    gemm_gateup<<<16384, 256, 0, stream>>>(
        xnh, xnl, wg + (long)l*NEXP*HDIM*FFDIM, wu + (long)l*NEXP*HDIM*FFDIM,
        ghi, glo, tok_of_pair, offs);
    gemm_down<<<2048, 256, 0, stream>>>(
        ghi, glo, wd + (long)l*NEXP*FFDIM*HDIM, po,
        offs, HDIM, FFDIM, (long)FFDIM*HDIM);
    combine_kernel<<<NTOK, 256, 0, stream>>>(x, po, tok_slot, tok_w);
  }
}

// Round 13
// 3304.618 us; speedup vs baseline: 1.0549x; 1.0549x over previous
//
#include <hip/hip_runtime.h>
#include <hip/hip_bf16.h>
#include <math.h>

typedef unsigned short u16;
typedef short short8 __attribute__((ext_vector_type(8)));
typedef short short4v __attribute__((ext_vector_type(4)));
typedef float f32x4 __attribute__((ext_vector_type(4)));

#define NLAYER 4
#define HDIM 1024
#define NHEAD 16
#define NKVH 4
#define FFDIM 2048
#define NEXP 8
#define SEQ 2048
#define NBATCH 2
#define NTOK (NBATCH*SEQ)
#define NPAIR (NTOK*2)
#define RMS_EPS 1e-5f

// ---- 2-term bf16 split via native cvt (RNE): x = b2f(o0)+b2f(o1)+O(x*2^-18) ----
__device__ __forceinline__ u16 b16(float x) {
  union { __hip_bfloat16 h; u16 u; } c;
  c.h = __float2bfloat16(x);
  return c.u;
}
__device__ __forceinline__ float b2f(u16 b) {
  return __builtin_bit_cast(float, ((unsigned)b) << 16);
}
__device__ __forceinline__ void split2(float x, u16& o0, u16& o1) {
  o0 = b16(x); o1 = b16(x - b2f(o0));
}
__device__ __forceinline__ float clip100(float v) {
  return fminf(fmaxf(v, -100.f), 100.f);
}
// chunked XCD swizzle (nwg % 8 == 0)
__device__ __forceinline__ int swz8(int bid, int nwg) {
  return (bid & 7) * (nwg >> 3) + (bid >> 3);
}

// ---------------- RMSNorm: fp32 -> pre-split bf16 hi/lo ----------------
__global__ __launch_bounds__(256)
void rmsnorm_kernel(const float* __restrict__ x, const float* __restrict__ w,
                    u16* __restrict__ oh, u16* __restrict__ ol) {
  int t = blockIdx.x, tid = threadIdx.x;
  const float* xr = x + (long)t * HDIM;
  float4 v = *(const float4*)(xr + tid * 4);
  float ss = v.x*v.x + v.y*v.y + v.z*v.z + v.w*v.w;
  #pragma unroll
  for (int m = 32; m; m >>= 1) ss += __shfl_xor(ss, m);
  __shared__ float sb[4];
  if ((tid & 63) == 0) sb[tid >> 6] = ss;
  __syncthreads();
  ss = sb[0] + sb[1] + sb[2] + sb[3];
  float sc = 1.0f / sqrtf(ss * (1.f/HDIM) + RMS_EPS);
  float4 wv = *(const float4*)(w + tid * 4);
  float ov[4] = {v.x*sc*wv.x, v.y*sc*wv.y, v.z*sc*wv.z, v.w*sc*wv.w};
  short4v hv, lv;
  #pragma unroll
  for (int j = 0; j < 4; j++) { u16 h, l; split2(ov[j], h, l); hv[j]=(short)h; lv[j]=(short)l; }
  *(short4v*)&oh[(long)t*HDIM + tid*4] = hv;
  *(short4v*)&ol[(long)t*HDIM + tid*4] = lv;
}

// ---------------- RoPE cos/sin table ----------------
__global__ __launch_bounds__(256)
void rope_table_kernel(float* __restrict__ tab) {
  int idx = blockIdx.x * 256 + threadIdx.x;   // SEQ*32
  int i = idx & 31, pos = idx >> 5;
  double e = -(double)i * 0.28782313662425575;   // ln(10000)/32
  float inv = (float)exp(e);
  float f = (float)pos * inv;
  tab[idx] = cosf(f);
  tab[SEQ*32 + idx] = sinf(f);
}

#define GPAD 40

// =========== pipelined GEMM core BM=128, BN=64 (wave = 32 rows x 64 cols) ==========
__device__ __forceinline__ void gemm_core128(
    const u16* __restrict__ Ah, const u16* __restrict__ Al, long arow,
    const float* __restrict__ Bp, int Nb, int bcol0, int K,
    u16 (&As)[2][128][GPAD], u16 (&Bs)[2][64][GPAD],
    int tid, int wr, int lr, int lg, f32x4 (&acc)[2][4])
{
  int a_r = tid >> 1, a_kq = (tid & 1) * 16;
  int b_col = tid & 63;
  int b_kh = (tid >> 6) * 8;
  short8 pA[4];
  float pB[8];
  short8 cBh, cBl;
  auto loadA = [&](int k0) {
    if (arow >= 0) {
      const u16* ah = Ah + arow * (long)K + k0 + a_kq;
      const u16* al = Al + arow * (long)K + k0 + a_kq;
      pA[0] = *(const short8*)ah;
      pA[1] = *(const short8*)(ah + 8);
      pA[2] = *(const short8*)al;
      pA[3] = *(const short8*)(al + 8);
    } else {
      short8 z = {0,0,0,0,0,0,0,0};
      #pragma unroll
      for (int q = 0; q < 4; q++) pA[q] = z;
    }
  };
  auto loadB = [&](int k0) {
    const float* bp = Bp + (long)(k0 + b_kh) * Nb + bcol0 + b_col;
    #pragma unroll
    for (int j = 0; j < 8; j++) pB[j] = bp[(long)j * Nb];
  };
  auto convB = [&]() {
    #pragma unroll
    for (int j = 0; j < 8; j++) {
      u16 h, l; split2(pB[j], h, l);
      cBh[j] = (short)h; cBl[j] = (short)l;
    }
  };
  loadA(0); loadB(0); convB();
  for (int k0 = 0; k0 < K; k0 += 32) {
    if (k0) __syncthreads();
    *(short8*)&As[0][a_r][a_kq]     = pA[0];
    *(short8*)&As[0][a_r][a_kq + 8] = pA[1];
    *(short8*)&As[1][a_r][a_kq]     = pA[2];
    *(short8*)&As[1][a_r][a_kq + 8] = pA[3];
    *(short8*)&Bs[0][b_col][b_kh] = cBh;
    *(short8*)&Bs[1][b_col][b_kh] = cBl;
    __syncthreads();
    int kn = k0 + 32;
    if (kn < K) { loadA(kn); loadB(kn); }
    short8 bf[2][4];
    #pragma unroll
    for (int t = 0; t < 2; t++)
      #pragma unroll
      for (int n = 0; n < 4; n++)
        bf[t][n] = *(const short8*)&Bs[t][n*16 + lr][lg*8];
    #pragma unroll
    for (int m = 0; m < 2; m++) {
      short8 afh = *(const short8*)&As[0][wr + m*16 + lr][lg*8];
      short8 afl = *(const short8*)&As[1][wr + m*16 + lr][lg*8];
      #pragma unroll
      for (int n = 0; n < 4; n++) {
        f32x4 a = acc[m][n];
        a = __builtin_amdgcn_mfma_f32_16x16x32_bf16(afh, bf[0][n], a, 0, 0, 0);
        a = __builtin_amdgcn_mfma_f32_16x16x32_bf16(afh, bf[1][n], a, 0, 0, 0);
        a = __builtin_amdgcn_mfma_f32_16x16x32_bf16(afl, bf[0][n], a, 0, 0, 0);
        acc[m][n] = a;
      }
    }
    if (kn < K) convB();
  }
}

// down-proj: BM=128, per-expert slot rows, Cf = acc.
__global__ __launch_bounds__(256)
void gemm_down(const u16* __restrict__ Ah, const u16* __restrict__ Al,
               const float* __restrict__ B, float* __restrict__ Cf,
               const int* __restrict__ offs, int N, int K, long bstride, int ncol)
{
  __shared__ u16 As[2][128][GPAD];
  __shared__ u16 Bs[2][64][GPAD];
  int nwg = gridDim.x;
  int bid = swz8(blockIdx.x, nwg);
  int cpe = nwg >> 3;
  int z = bid / cpe, rr2 = bid % cpe;
  int rs = offs[z], re = offs[z + 1];
  int brow = rr2 / ncol, bcol = rr2 % ncol;
  int p0 = rs + brow * 128;
  if (p0 >= re) return;
  int bcol0 = bcol * 64;
  const float* Bp = B + (long)z * bstride;
  int tid = threadIdx.x, wv = tid >> 6, lane = tid & 63;
  int lr = lane & 15, lg = lane >> 4;
  int wr = wv * 32;
  long arow = -1;
  { int rr = p0 + (tid >> 1); if (rr < re) arow = rr; }
  f32x4 acc[2][4];
  #pragma unroll
  for (int m = 0; m < 2; m++)
    #pragma unroll
    for (int n = 0; n < 4; n++) acc[m][n] = {0.f,0.f,0.f,0.f};
  gemm_core128(Ah, Al, arow, Bp, N, bcol0, K, As, Bs, tid, wr, lr, lg, acc);
  #pragma unroll
  for (int m = 0; m < 2; m++) {
    int row0 = p0 + wr + m*16 + lg*4;
    #pragma unroll
    for (int n = 0; n < 4; n++) {
      int col = bcol0 + n*16 + lr;
      #pragma unroll
      for (int r = 0; r < 4; r++) {
        int row = row0 + r;
        if (row < re) Cf[(long)row * N + col] = acc[m][n][r];
      }
    }
  }
}

// wo-proj: BM=128, Cf = clip(Cf + acc).
__global__ __launch_bounds__(256)
void gemm_wo(const u16* __restrict__ Ah, const u16* __restrict__ Al,
             const float* __restrict__ B, float* __restrict__ Cf,
             int M, int N, int K, int ncol)
{
  __shared__ u16 As[2][128][GPAD];
  __shared__ u16 Bs[2][64][GPAD];
  int bid = swz8(blockIdx.x, gridDim.x);
  int brow = bid / ncol, bcol = bid % ncol;
  int p0 = brow * 128;
  int bcol0 = bcol * 64;
  int tid = threadIdx.x, wv = tid >> 6, lane = tid & 63;
  int lr = lane & 15, lg = lane >> 4;
  int wr = wv * 32;
  long arow = p0 + (tid >> 1);
  f32x4 acc[2][4];
  #pragma unroll
  for (int m = 0; m < 2; m++)
    #pragma unroll
    for (int n = 0; n < 4; n++) acc[m][n] = {0.f,0.f,0.f,0.f};
  gemm_core128(Ah, Al, arow, B, N, bcol0, K, As, Bs, tid, wr, lr, lg, acc);
  #pragma unroll
  for (int m = 0; m < 2; m++) {
    int row0 = p0 + wr + m*16 + lg*4;
    #pragma unroll
    for (int n = 0; n < 4; n++) {
      int col = bcol0 + n*16 + lr;
      #pragma unroll
      for (int r = 0; r < 4; r++) {
        long idx = (long)(row0 + r) * N + col;
        Cf[idx] = clip100(Cf[idx] + acc[m][n][r]);
      }
    }
  }
}

// ---------- fused MoE gate+up GEMM, BM=128 (64 AGPR -> 3 waves/SIMD) ----------
// h = silu(x@wg) * (x@wu), pre-split bf16 hi/lo output.
__global__ __launch_bounds__(256)
void gemm_gateup(const u16* __restrict__ Ah, const u16* __restrict__ Al,
                 const float* __restrict__ Bg, const float* __restrict__ Bu,
                 u16* __restrict__ Ch, u16* __restrict__ Cl,
                 const int* __restrict__ gather, const int* __restrict__ offs)
{
  __shared__ u16 As[2][128][GPAD];
  __shared__ u16 Bgs[2][64][GPAD];
  __shared__ u16 Bus[2][64][GPAD];
  const int K = HDIM, N = FFDIM;
  int nwg = gridDim.x;                    // 16384 = 8 exp * 64 row * 32 col
  int bid = swz8(blockIdx.x, nwg);
  int cpe = nwg >> 3;                     // 2048 per expert
  int z = bid / cpe, rr2 = bid % cpe;
  int rs = offs[z], re = offs[z + 1];
  int brow = rr2 >> 5, bcol = rr2 & 31;
  int p0 = rs + brow * 128;
  if (p0 >= re) return;
  int bcol0 = bcol * 64;
  const float* Bpg = Bg + (long)z * ((long)HDIM * FFDIM);
  const float* Bpu = Bu + (long)z * ((long)HDIM * FFDIM);
  int tid = threadIdx.x, wv = tid >> 6, lane = tid & 63;
  int lr = lane & 15, lg = lane >> 4;
  int wr = wv * 32;
  int a_r = tid >> 1, a_kq = (tid & 1) * 16;
  long arow = -1;
  { int rr = p0 + a_r; if (rr < re) arow = gather[rr]; }
  f32x4 accg[2][4], accu[2][4];
  #pragma unroll
  for (int m = 0; m < 2; m++)
    #pragma unroll
    for (int n = 0; n < 4; n++) { accg[m][n] = {0.f,0.f,0.f,0.f}; accu[m][n] = {0.f,0.f,0.f,0.f}; }
  int b_col = tid & 63;
  int b_kh = (tid >> 6) * 8;
  short8 pA[4];
  float pBg[8], pBu[8];
  short8 cGh, cGl, cUh, cUl;
  auto loadA = [&](int k0) {
    if (arow >= 0) {
      const u16* ah = Ah + arow * (long)K + k0 + a_kq;
      const u16* al = Al + arow * (long)K + k0 + a_kq;
      pA[0] = *(const short8*)ah;
      pA[1] = *(const short8*)(ah + 8);
      pA[2] = *(const short8*)al;
      pA[3] = *(const short8*)(al + 8);
    } else {
      short8 zz = {0,0,0,0,0,0,0,0};
      #pragma unroll
      for (int q = 0; q < 4; q++) pA[q] = zz;
    }
  };
  auto loadB = [&](int k0) {
    const float* bpg = Bpg + (long)(k0 + b_kh) * N + bcol0 + b_col;
    const float* bpu = Bpu + (long)(k0 + b_kh) * N + bcol0 + b_col;
    #pragma unroll
    for (int j = 0; j < 8; j++) { pBg[j] = bpg[(long)j * N]; pBu[j] = bpu[(long)j * N]; }
  };
  auto convB = [&]() {
    #pragma unroll
    for (int j = 0; j < 8; j++) {
      u16 h, l;
      split2(pBg[j], h, l); cGh[j] = (short)h; cGl[j] = (short)l;
      split2(pBu[j], h, l); cUh[j] = (short)h; cUl[j] = (short)l;
    }
  };
  loadA(0); loadB(0); convB();
  for (int k0 = 0; k0 < K; k0 += 32) {
    if (k0) __syncthreads();
    *(short8*)&As[0][a_r][a_kq]     = pA[0];
    *(short8*)&As[0][a_r][a_kq + 8] = pA[1];
    *(short8*)&As[1][a_r][a_kq]     = pA[2];
    *(short8*)&As[1][a_r][a_kq + 8] = pA[3];
    *(short8*)&Bgs[0][b_col][b_kh] = cGh;
    *(short8*)&Bgs[1][b_col][b_kh] = cGl;
    *(short8*)&Bus[0][b_col][b_kh] = cUh;
    *(short8*)&Bus[1][b_col][b_kh] = cUl;
    __syncthreads();
    int kn = k0 + 32;
    if (kn < K) { loadA(kn); loadB(kn); }
    short8 afh[2], afl[2];
    #pragma unroll
    for (int m = 0; m < 2; m++) {
      afh[m] = *(const short8*)&As[0][wr + m*16 + lr][lg*8];
      afl[m] = *(const short8*)&As[1][wr + m*16 + lr][lg*8];
    }
    #pragma unroll
    for (int n = 0; n < 4; n++) {
      short8 bgh = *(const short8*)&Bgs[0][n*16 + lr][lg*8];
      short8 bgl = *(const short8*)&Bgs[1][n*16 + lr][lg*8];
      short8 buh = *(const short8*)&Bus[0][n*16 + lr][lg*8];
      short8 bul = *(const short8*)&Bus[1][n*16 + lr][lg*8];
      #pragma unroll
      for (int m = 0; m < 2; m++) {
        f32x4 g = accg[m][n];
        g = __builtin_amdgcn_mfma_f32_16x16x32_bf16(afh[m], bgh, g, 0, 0, 0);
        g = __builtin_amdgcn_mfma_f32_16x16x32_bf16(afh[m], bgl, g, 0, 0, 0);
        g = __builtin_amdgcn_mfma_f32_16x16x32_bf16(afl[m], bgh, g, 0, 0, 0);
        accg[m][n] = g;
        f32x4 u = accu[m][n];
        u = __builtin_amdgcn_mfma_f32_16x16x32_bf16(afh[m], buh, u, 0, 0, 0);
        u = __builtin_amdgcn_mfma_f32_16x16x32_bf16(afh[m], bul, u, 0, 0, 0);
        u = __builtin_amdgcn_mfma_f32_16x16x32_bf16(afl[m], buh, u, 0, 0, 0);
        accu[m][n] = u;
      }
    }
    if (kn < K) convB();
  }
  #pragma unroll
  for (int m = 0; m < 2; m++) {
    int row0 = p0 + wr + m*16 + lg*4;
    #pragma unroll
    for (int n = 0; n < 4; n++) {
      int col = bcol0 + n*16 + lr;
      #pragma unroll
      for (int r = 0; r < 4; r++) {
        int row = row0 + r;
        if (row < re) {
          float gv = accg[m][n][r], uv = accu[m][n][r];
          float hh = gv / (1.f + __expf(-gv)) * uv;
          u16 h, l; split2(hh, h, l);
          long idx = (long)row * N + col;
          Ch[idx] = h; Cl[idx] = l;
        }
      }
    }
  }
}

// fused QKV GEMM: BM=128, 1D grid 768 (bx 0..23 fast, 32 row panels), XCD swizzled
__global__ __launch_bounds__(256)
void gemm_qkv(const u16* __restrict__ Ah, const u16* __restrict__ Al,
              const float* __restrict__ wq, const float* __restrict__ wk,
              const float* __restrict__ wv_, const float* __restrict__ tab,
              u16* __restrict__ qh, u16* __restrict__ ql,
              u16* __restrict__ kh_, u16* __restrict__ kl_,
              u16* __restrict__ vth, u16* __restrict__ vtl)
{
  __shared__ u16 As[2][128][GPAD];
  __shared__ u16 Bs[2][64][GPAD];
  int bid = swz8(blockIdx.x, gridDim.x);
  int bx = bid % 24;
  int p0 = (bid / 24) * 128;
  const float* Bp; int Nb, bcol0;
  if (bx < 16)      { Bp = wq;  Nb = 1024; bcol0 = bx * 64; }
  else if (bx < 20) { Bp = wk;  Nb = 256;  bcol0 = (bx - 16) * 64; }
  else              { Bp = wv_; Nb = 256;  bcol0 = (bx - 20) * 64; }
  int K = HDIM;
  int tid = threadIdx.x, wv = tid >> 6, lane = tid & 63;
  int lr = lane & 15, lg = lane >> 4;
  int wr = wv * 32;
  long arow = p0 + (tid >> 1);
  f32x4 acc[2][4];
  #pragma unroll
  for (int m = 0; m < 2; m++)
    #pragma unroll
    for (int n = 0; n < 4; n++) acc[m][n] = {0.f,0.f,0.f,0.f};
  gemm_core128(Ah, Al, arow, Bp, Nb, bcol0, K, As, Bs, tid, wr, lr, lg, acc);
  if (bx < 16) {          // ---- q: rope + split ----
    int h = bx;
    #pragma unroll
    for (int m = 0; m < 2; m++) {
      #pragma unroll
      for (int r = 0; r < 4; r++) {
        int tok = p0 + wr + m*16 + lg*4 + r;
        int pos = tok & (SEQ - 1);
        #pragma unroll
        for (int n = 0; n < 2; n++) {
          int i = n*16 + lr;
          float c = tab[pos*32 + i], s = tab[SEQ*32 + pos*32 + i];
          float x0 = acc[m][n][r], x1 = acc[m][n+2][r];
          float y0 = x0*c - x1*s, y1 = x1*c + x0*s;
          long base = (long)tok*1024 + h*64 + i;
          u16 h0, l0; split2(y0, h0, l0); qh[base] = h0; ql[base] = l0;
          u16 h1, l1; split2(y1, h1, l1); qh[base+32] = h1; ql[base+32] = l1;
        }
      }
    }
  } else if (bx < 20) {   // ---- k: rope + split ----
    int kvh = bx - 16;
    #pragma unroll
    for (int m = 0; m < 2; m++) {
      #pragma unroll
      for (int r = 0; r < 4; r++) {
        int tok = p0 + wr + m*16 + lg*4 + r;
        int pos = tok & (SEQ - 1);
        #pragma unroll
        for (int n = 0; n < 2; n++) {
          int i = n*16 + lr;
          float c = tab[pos*32 + i], s = tab[SEQ*32 + pos*32 + i];
          float x0 = acc[m][n][r], x1 = acc[m][n+2][r];
          float y0 = x0*c - x1*s, y1 = x1*c + x0*s;
          long base = (long)tok*256 + kvh*64 + i;
          u16 h0, l0; split2(y0, h0, l0); kh_[base] = h0; kl_[base] = l0;
          u16 h1, l1; split2(y1, h1, l1); kh_[base+32] = h1; kl_[base+32] = l1;
        }
      }
    }
  } else {                // ---- v: split + transpose ----
    int kvh = bx - 20;
    #pragma unroll
    for (int m = 0; m < 2; m++) {
      #pragma unroll
      for (int r = 0; r < 4; r++) {
        int tok = p0 + wr + m*16 + lg*4 + r;
        int bb = tok >> 11, tl = tok & (SEQ - 1);
        #pragma unroll
        for (int n = 0; n < 4; n++) {
          int hd = n*16 + lr;
          u16 h0, l0; split2(acc[m][n][r], h0, l0);
          long vidx = ((long)(bb*NKVH + kvh)*64 + hd)*SEQ + tl;
          vth[vidx] = h0; vtl[vidx] = l0;
        }
      }
    }
  }
}

// ---------------- causal flash attention, pipelined K/V staging ----------------
#define ATP 70
#define PPAD 68
__global__ __launch_bounds__(256)
void attn_kernel(const u16* __restrict__ qhi, const u16* __restrict__ qlo,
                 const u16* __restrict__ khi, const u16* __restrict__ klo,
                 const u16* __restrict__ vthi, const u16* __restrict__ vtlo,
                 u16* __restrict__ ohi, u16* __restrict__ olo)
{
  int bid = swz8(blockIdx.x, gridDim.x);   // chunk 64 = one (b, kvh) group
  int qp = bid & 15, h = (bid >> 4) & 15, b = bid >> 8;
  int kvh = h >> 2;
  int tid = threadIdx.x, w = tid >> 6, lane = tid & 63;
  int lr = lane & 15, lg = lane >> 4;
  __shared__ u16 KhS[64][ATP], KlS[64][ATP], VhS[64][ATP], VlS[64][ATP];
  __shared__ u16 Ps[2][4][16][PPAD];
  long tokbase = (long)b * SEQ;
  int sr = tid >> 2, scg = (tid & 3) * 16;
  const u16* vrow_h = vthi + ((long)(b*NKVH + kvh)*64 + sr)*SEQ;
  const u16* vrow_l = vtlo + ((long)(b*NKVH + kvh)*64 + sr)*SEQ;
  short8 pK[4], pV[4];
  auto loadKV = [&](int kt) {
    long kg = (tokbase + kt*64 + sr)*256 + kvh*64 + scg;
    pK[0] = *(const short8*)(khi + kg);
    pK[1] = *(const short8*)(khi + kg + 8);
    pK[2] = *(const short8*)(klo + kg);
    pK[3] = *(const short8*)(klo + kg + 8);
    long vg = kt*64 + scg;
    pV[0] = *(const short8*)(vrow_h + vg);
    pV[1] = *(const short8*)(vrow_h + vg + 8);
    pV[2] = *(const short8*)(vrow_l + vg);
    pV[3] = *(const short8*)(vrow_l + vg + 8);
  };
  loadKV(0);

  for (int ph = 0; ph < 2; ph++) {
    int qt = ph ? (31 - qp) : qp;
    long q0 = (long)qt * 64;
    const u16* qh_row = qhi + (tokbase + q0 + w*16 + lr)*1024 + h*64;
    const u16* ql_row = qlo + (tokbase + q0 + w*16 + lr)*1024 + h*64;
    short8 aqh[2], aql[2];
    #pragma unroll
    for (int hf = 0; hf < 2; hf++) {
      aqh[hf] = *(const short8*)(qh_row + hf*32 + lg*8);
      aql[hf] = *(const short8*)(ql_row + hf*32 + lg*8);
    }
    f32x4 Oacc[4];
    #pragma unroll
    for (int n = 0; n < 4; n++) Oacc[n] = {0.f,0.f,0.f,0.f};
    float mrow[4] = {-1e30f,-1e30f,-1e30f,-1e30f};
    float lrow[4] = {0.f,0.f,0.f,0.f};
    for (int kt = 0; kt <= qt; kt++) {
      if (ph | kt) __syncthreads();     // prior LDS readers done
      *(short8*)&KhS[sr][scg]   = pK[0];
      *(short8*)&KhS[sr][scg+8] = pK[1];
      *(short8*)&KlS[sr][scg]   = pK[2];
      *(short8*)&KlS[sr][scg+8] = pK[3];
      *(short8*)&VhS[sr][scg]   = pV[0];
      *(short8*)&VhS[sr][scg+8] = pV[1];
      *(short8*)&VlS[sr][scg]   = pV[2];
      *(short8*)&VlS[sr][scg+8] = pV[3];
      __syncthreads();
      loadKV(kt < qt ? kt + 1 : 0);     // prefetch next tile (or next phase's 0)
      float sv[4][4];
      #pragma unroll
      for (int n = 0; n < 4; n++) {
        short8 bh0 = *(const short8*)&KhS[n*16 + lr][lg*8];
        short8 bh1 = *(const short8*)&KhS[n*16 + lr][32 + lg*8];
        short8 bl0 = *(const short8*)&KlS[n*16 + lr][lg*8];
        short8 bl1 = *(const short8*)&KlS[n*16 + lr][32 + lg*8];
        f32x4 c = {0.f,0.f,0.f,0.f};
        c = __builtin_amdgcn_mfma_f32_16x16x32_bf16(aqh[0], bh0, c, 0, 0, 0);
        c = __builtin_amdgcn_mfma_f32_16x16x32_bf16(aqh[1], bh1, c, 0, 0, 0);
        c = __builtin_amdgcn_mfma_f32_16x16x32_bf16(aqh[0], bl0, c, 0, 0, 0);
        c = __builtin_amdgcn_mfma_f32_16x16x32_bf16(aqh[1], bl1, c, 0, 0, 0);
        c = __builtin_amdgcn_mfma_f32_16x16x32_bf16(aql[0], bh0, c, 0, 0, 0);
        c = __builtin_amdgcn_mfma_f32_16x16x32_bf16(aql[1], bh1, c, 0, 0, 0);
        #pragma unroll
        for (int r = 0; r < 4; r++) sv[n][r] = c[r] * 0.125f;
      }
      if (kt == qt) {
        #pragma unroll
        for (int n = 0; n < 4; n++)
          #pragma unroll
          for (int r = 0; r < 4; r++)
            if (n*16 + lr > w*16 + lg*4 + r) sv[n][r] = -1e30f;
      }
      float pvv[4][4], alpha[4];
      #pragma unroll
      for (int r = 0; r < 4; r++) {
        float vm = fmaxf(fmaxf(sv[0][r], sv[1][r]), fmaxf(sv[2][r], sv[3][r]));
        #pragma unroll
        for (int msk = 1; msk < 16; msk <<= 1) vm = fmaxf(vm, __shfl_xor(vm, msk));
        float mnew = fmaxf(mrow[r], vm);
        alpha[r] = __expf(mrow[r] - mnew);
        float psum = 0.f;
        #pragma unroll
        for (int n = 0; n < 4; n++) { pvv[n][r] = __expf(sv[n][r] - mnew); psum += pvv[n][r]; }
        #pragma unroll
        for (int msk = 1; msk < 16; msk <<= 1) psum += __shfl_xor(psum, msk);
        lrow[r] = lrow[r] * alpha[r] + psum;
        mrow[r] = mnew;
      }
      #pragma unroll
      for (int n = 0; n < 4; n++)
        #pragma unroll
        for (int r = 0; r < 4; r++) {
          u16 t0, t1;
          split2(pvv[n][r], t0, t1);
          Ps[0][w][lg*4 + r][n*16 + lr] = t0;
          Ps[1][w][lg*4 + r][n*16 + lr] = t1;
        }
      #pragma unroll
      for (int n = 0; n < 4; n++)
        #pragma unroll
        for (int r = 0; r < 4; r++) Oacc[n][r] *= alpha[r];
      #pragma unroll
      for (int kk = 0; kk < 2; kk++) {
        short8 aph = *(const short8*)&Ps[0][w][lr][kk*32 + lg*8];
        short8 apl = *(const short8*)&Ps[1][w][lr][kk*32 + lg*8];
        #pragma unroll
        for (int n = 0; n < 4; n++) {
          short8 bvh = *(const short8*)&VhS[n*16 + lr][kk*32 + lg*8];
          short8 bvl = *(const short8*)&VlS[n*16 + lr][kk*32 + lg*8];
          f32x4 a = Oacc[n];
          a = __builtin_amdgcn_mfma_f32_16x16x32_bf16(aph, bvh, a, 0, 0, 0);
          a = __builtin_amdgcn_mfma_f32_16x16x32_bf16(aph, bvl, a, 0, 0, 0);
          a = __builtin_amdgcn_mfma_f32_16x16x32_bf16(apl, bvh, a, 0, 0, 0);
          Oacc[n] = a;
        }
      }
    }
    u16* oh_row = ohi + (tokbase + q0 + w*16)*1024 + h*64;
    u16* ol_row = olo + (tokbase + q0 + w*16)*1024 + h*64;
    #pragma unroll
    for (int n = 0; n < 4; n++)
      #pragma unroll
      for (int r = 0; r < 4; r++) {
        float v = Oacc[n][r] / lrow[r];
        u16 h0, l0; split2(v, h0, l0);
        oh_row[(lg*4 + r)*1024 + n*16 + lr] = h0;
        ol_row[(lg*4 + r)*1024 + n*16 + lr] = l0;
      }
  }
}

// ---------------- router (pure fp32) ----------------
__global__ __launch_bounds__(64)
void router_kernel(const float* __restrict__ x, const float* __restrict__ w2,
                   const float* __restrict__ wr, int* __restrict__ tok_e,
                   float* __restrict__ tok_w, int* __restrict__ counts)
{
  int t = blockIdx.x, l = threadIdx.x;
  const float* xr = x + (long)t * HDIM;
  float xv[16];
  float ss = 0.f;
  #pragma unroll
  for (int j = 0; j < 16; j++) { xv[j] = xr[l + j*64]; ss += xv[j]*xv[j]; }
  #pragma unroll
  for (int m = 32; m; m >>= 1) ss += __shfl_xor(ss, m);
  float sc = 1.0f / sqrtf(ss * (1.f/HDIM) + RMS_EPS);
  float acc[8] = {0,0,0,0,0,0,0,0};
  #pragma unroll
  for (int j = 0; j < 16; j++) {
    int hh = l + j*64;
    float xnv = xv[j] * sc * w2[hh];
    const float* wrow = wr + hh * 8;
    #pragma unroll
    for (int e = 0; e < 8; e++) acc[e] += xnv * wrow[e];
  }
  #pragma unroll
  for (int e = 0; e < 8; e++)
    #pragma unroll
    for (int m = 32; m; m >>= 1) acc[e] += __shfl_xor(acc[e], m);
  if (l == 0) {
    float mx = acc[0];
    #pragma unroll
    for (int e = 1; e < 8; e++) mx = fmaxf(mx, acc[e]);
    float ex[8], s = 0.f;
    #pragma unroll
    for (int e = 0; e < 8; e++) { ex[e] = expf(acc[e] - mx); s += ex[e]; }
    int e0 = 0;
    #pragma unroll
    for (int e = 1; e < 8; e++) if (ex[e] > ex[e0]) e0 = e;
    int e1 = (e0 == 0) ? 1 : 0;
    for (int e = 0; e < 8; e++) if (e != e0 && ex[e] > ex[e1]) e1 = e;
    float v0 = ex[e0] / s, v1 = ex[e1] / s, wsum = v0 + v1;
    tok_e[2*t] = e0; tok_e[2*t+1] = e1;
    tok_w[2*t] = v0 / wsum; tok_w[2*t+1] = v1 / wsum;
    atomicAdd(&counts[e0], 1);
    atomicAdd(&counts[e1], 1);
  }
}

__global__ void scan_kernel(const int* __restrict__ counts, int* __restrict__ offs,
                            int* __restrict__ cursor) {
  if (threadIdx.x == 0 && blockIdx.x == 0) {
    int s = 0;
    for (int e = 0; e < NEXP; e++) { offs[e] = s; cursor[e] = s; s += counts[e]; }
    offs[NEXP] = s;
  }
}

__global__ __launch_bounds__(256)
void scatter_kernel(const int* __restrict__ tok_e, int* __restrict__ cursor,
                    int* __restrict__ tok_of_pair, int* __restrict__ tok_slot) {
  int t = blockIdx.x * 256 + threadIdx.x;
  if (t >= NTOK) return;
  #pragma unroll
  for (int s = 0; s < 2; s++) {
    int e = tok_e[2*t + s];
    int pos = atomicAdd(&cursor[e], 1);
    tok_of_pair[pos] = t;
    tok_slot[2*t + s] = pos;
  }
}

// x = clip(x + w0*po[s0] + w1*po[s1])
__global__ __launch_bounds__(256)
void combine_kernel(float* __restrict__ x, const float* __restrict__ po,
                    const int* __restrict__ tok_slot, const float* __restrict__ tok_w) {
  int t = blockIdx.x, tid = threadIdx.x;
  long s0 = tok_slot[2*t], s1 = tok_slot[2*t+1];
  float w0 = tok_w[2*t], w1 = tok_w[2*t+1];
  int c = tid * 4;
  float4 xv = *(float4*)(x + (long)t*HDIM + c);
  float4 a  = *(const float4*)(po + s0*HDIM + c);
  float4 bb = *(const float4*)(po + s1*HDIM + c);
  xv.x = clip100(xv.x + w0*a.x + w1*bb.x);
  xv.y = clip100(xv.y + w0*a.y + w1*bb.y);
  xv.z = clip100(xv.z + w0*a.z + w1*bb.z);
  xv.w = clip100(xv.w + w0*a.w + w1*bb.w);
  *(float4*)(x + (long)t*HDIM + c) = xv;
}

extern "C" void kernel_launch(void* const* d_in, const int* in_sizes, int n_in,
                              void* d_out, int out_size, void* d_ws, size_t ws_size,
                              hipStream_t stream)
{
  (void)in_sizes; (void)n_in; (void)out_size; (void)ws_size;
  const float* hs  = (const float*)d_in[0];
  const float* ln1 = (const float*)d_in[1];
  const float* ln2 = (const float*)d_in[2];
  const float* wq  = (const float*)d_in[3];
  const float* wk  = (const float*)d_in[4];
  const float* wvv = (const float*)d_in[5];
  const float* wo  = (const float*)d_in[6];
  const float* wr  = (const float*)d_in[7];
  const float* wg  = (const float*)d_in[8];
  const float* wu  = (const float*)d_in[9];
  const float* wd  = (const float*)d_in[10];
  float* x = (float*)d_out;

  char* p = (char*)d_ws;
  auto carve = [&](size_t bytes) {
    char* r = p; p += (bytes + 255) & ~(size_t)255; return r;
  };
  float* tab = (float*)carve((size_t)SEQ * 32 * 2 * 4);
  u16* xnh = (u16*)carve((size_t)NTOK * HDIM * 2);
  u16* xnl = (u16*)carve((size_t)NTOK * HDIM * 2);
  char* R  = carve((size_t)128 * 1024 * 1024);   // shared attn / MoE region
  // attn phase layout
  u16* qhi = (u16*)R;                              // 8MB
  u16* qlo = (u16*)(R + 8u*1024*1024);             // 8MB
  u16* khi = (u16*)(R + 16u*1024*1024);            // 2MB
  u16* klo = (u16*)(R + 18u*1024*1024);            // 2MB
  u16* vthi= (u16*)(R + 20u*1024*1024);            // 2MB
  u16* vtlo= (u16*)(R + 22u*1024*1024);            // 2MB
  u16* ohi = (u16*)(R + 24u*1024*1024);            // 8MB
  u16* olo = (u16*)(R + 32u*1024*1024);            // 8MB
  // MoE phase layout (aliases attn; sequential stream order makes this safe)
  u16*   ghi = (u16*)R;                            // 32MB
  u16*   glo = (u16*)(R + 32u*1024*1024);          // 32MB
  float* po  = (float*)(R + 64u*1024*1024);        // 32MB
  int*   tok_e       = (int*)carve(NTOK * 2 * 4);
  float* tok_w       = (float*)carve(NTOK * 2 * 4);
  int*   tok_slot    = (int*)carve(NTOK * 2 * 4);
  int*   tok_of_pair = (int*)carve(NPAIR * 4);
  int*   counts      = (int*)carve(8 * 4);
  int*   offs        = (int*)carve(9 * 4);
  int*   cursor      = (int*)carve(8 * 4);

  hipMemcpyAsync(x, hs, (size_t)NTOK * HDIM * 4, hipMemcpyDeviceToDevice, stream);
  rope_table_kernel<<<SEQ*32/256, 256, 0, stream>>>(tab);

  for (int l = 0; l < NLAYER; l++) {
    rmsnorm_kernel<<<NTOK, 256, 0, stream>>>(x, ln1 + (long)l*HDIM, xnh, xnl);
    gemm_qkv<<<768, 256, 0, stream>>>(
        xnh, xnl, wq + (long)l*HDIM*1024, wk + (long)l*HDIM*256,
        wvv + (long)l*HDIM*256, tab, qhi, qlo, khi, klo, vthi, vtlo);
    attn_kernel<<<512, 256, 0, stream>>>(
        qhi, qlo, khi, klo, vthi, vtlo, ohi, olo);
    gemm_wo<<<512, 256, 0, stream>>>(
        ohi, olo, wo + (long)l*1024*HDIM, x, NTOK, HDIM, 1024, 16);

    rmsnorm_kernel<<<NTOK, 256, 0, stream>>>(x, ln2 + (long)l*HDIM, xnh, xnl);
    hipMemsetAsync(counts, 0, 8 * 4, stream);
    router_kernel<<<NTOK, 64, 0, stream>>>(
        x, ln2 + (long)l*HDIM, wr + (long)l*HDIM*NEXP, tok_e, tok_w, counts);
    scan_kernel<<<1, 64, 0, stream>>>(counts, offs, cursor);
    scatter_kernel<<<NTOK/256, 256, 0, stream>>>(tok_e, cursor, tok_of_pair, tok_slot);
    gemm_gateup<<<16384, 256, 0, stream>>>(
        xnh, xnl, wg + (long)l*NEXP*HDIM*FFDIM, wu + (long)l*NEXP*HDIM*FFDIM,
        ghi, glo, tok_of_pair, offs);
    gemm_down<<<8192, 256, 0, stream>>>(
        ghi, glo, wd + (long)l*NEXP*FFDIM*HDIM, po,
        offs, HDIM, FFDIM, (long)FFDIM*HDIM, 16);
    combine_kernel<<<NTOK, 256, 0, stream>>>(x, po, tok_slot, tok_w);
  }
}